// Round 19
// baseline (478.442 us; speedup 1.0000x reference)
//
#include <hip/hip_runtime.h>
#include <hip/hip_bf16.h>

#define N_NODES 30000
#define N_GRAPHS 256
#define HEADS 4
#define NBLK_SCAN ((N_NODES + 255) / 256)   // 118

typedef __attribute__((ext_vector_type(8))) short short8;
typedef __attribute__((ext_vector_type(4))) float f32x4;
typedef __attribute__((ext_vector_type(4))) unsigned short ushort4_t;
typedef unsigned short ushort_t;

__device__ __forceinline__ ushort_t f2bf(float v) {
    __hip_bfloat16 h = __float2bfloat16(v);
    return *reinterpret_cast<ushort_t*>(&h);
}
__device__ __forceinline__ float bf2f(ushort_t u) {
    __hip_bfloat16 h;
    *reinterpret_cast<ushort_t*>(&h) = u;
    return __bfloat162float(h);
}
__device__ __forceinline__ int ld_idx(const void* p, long i, int is64) {
    return is64 ? (int)((const long long*)p)[i] : ((const int*)p)[i];
}
__device__ __forceinline__ int clampi(int v, int hi) {
    return v < 0 ? 0 : (v > hi ? hi : v);
}

// ---------------------------------------------------------------------------
__global__ void detect_fmt(const void* ei, const void* batch, int E, int* flags)
{
    __shared__ int okE, okB;
    if (threadIdx.x == 0) { okE = 1; okB = 1; }
    __syncthreads();
    const long long* e64 = (const long long*)ei;
    const long long* b64 = (const long long*)batch;
    const int nbslot = N_NODES / 2;
    for (int i = threadIdx.x; i < 2048; i += 256) {
        long ei_idx = (long)i * E / 2048;
        long long v = e64[ei_idx];
        if (v < 0 || v >= N_NODES) okE = 0;
        long b_idx = (long)i * nbslot / 2048;
        long long b = b64[b_idx];
        if (b < 0 || b >= N_GRAPHS) okB = 0;
    }
    __syncthreads();
    if (threadIdx.x == 0) { flags[0] = okE; flags[1] = okB; }
}

// ---------------------------------------------------------------------------
__global__ void init_zero(int* __restrict__ indeg, int* __restrict__ gcnt)
{
    int i = blockIdx.x * 256 + threadIdx.x;
    if (i < N_NODES) indeg[i] = 0;
    if (i < N_GRAPHS) gcnt[i] = 0;
}

__global__ void zero_pads(ushort_t* __restrict__ H1b, ushort_t* __restrict__ H2b)
{
    int n = blockIdx.x * blockDim.x + threadIdx.x;
    if (n >= N_NODES) return;
    ushort4_t z = {0, 0, 0, 0};
    *(ushort4_t*)&H1b[(long)n * 320 + 312] = z;
    *(ushort4_t*)&H1b[(long)n * 320 + 316] = z;
#pragma unroll
    for (int q = 0; q < 4; ++q)
        *(ushort4_t*)&H2b[(long)n * 640 + 624 + q * 4] = z;
}

// ---------------------------------------------------------------------------
__global__ void csr_hist(const void* ei, const void* batch, const int* __restrict__ flags,
                         int* __restrict__ indeg, int* __restrict__ gcnt, int E)
{
    int i = blockIdx.x * blockDim.x + threadIdx.x;
    if (i < E) {
        int d = clampi(ld_idx(ei, (long)E + i, flags[0]), N_NODES - 1);
        atomicAdd(&indeg[d], 1);
    }
    if (i < N_NODES) {
        int g = clampi(ld_idx(batch, i, flags[1]), N_GRAPHS - 1);
        atomicAdd(&gcnt[g], 1);
    }
}

// ---------------------------------------------------------------------------
// 3-phase coalesced device scan
// ---------------------------------------------------------------------------
__global__ __launch_bounds__(256) void scan_a(const int* __restrict__ indeg,
                                              int* __restrict__ locpre,
                                              int* __restrict__ bsum)
{
    __shared__ int ps[256];
    const int t = threadIdx.x;
    const int i = blockIdx.x * 256 + t;
    int v = (i < N_NODES) ? indeg[i] : 0;
    ps[t] = v;
    __syncthreads();
    for (int d = 1; d < 256; d <<= 1) {
        int u = (t >= d) ? ps[t - d] : 0;
        __syncthreads();
        ps[t] += u;
        __syncthreads();
    }
    if (i < N_NODES) locpre[i] = ps[t] - v;
    if (t == 255) bsum[blockIdx.x] = ps[255];
}

__global__ __launch_bounds__(256) void scan_b(const int* __restrict__ bsum,
                                              int* __restrict__ bbase,
                                              int* __restrict__ totE,
                                              const int* __restrict__ gcnt,
                                              int* __restrict__ gstart)
{
    __shared__ int ps[256];
    const int t = threadIdx.x;
    int v = (t < NBLK_SCAN) ? bsum[t] : 0;
    ps[t] = v;
    __syncthreads();
    for (int d = 1; d < 256; d <<= 1) {
        int u = (t >= d) ? ps[t - d] : 0;
        __syncthreads();
        ps[t] += u;
        __syncthreads();
    }
    if (t < NBLK_SCAN) bbase[t] = ps[t] - v;
    if (t == 255) totE[0] = ps[255];
    __syncthreads();
    int gv = gcnt[t];
    ps[t] = gv;
    __syncthreads();
    for (int d = 1; d < 256; d <<= 1) {
        int u = (t >= d) ? ps[t - d] : 0;
        __syncthreads();
        ps[t] += u;
        __syncthreads();
    }
    gstart[t + 1] = ps[t];
    if (t == 0) gstart[0] = 0;
}

__global__ void scan_c(const int* __restrict__ locpre, const int* __restrict__ bbase,
                       const int* __restrict__ totE,
                       int* __restrict__ off, int* __restrict__ cursor)
{
    int i = blockIdx.x * 256 + threadIdx.x;
    if (i < N_NODES) {
        int o = locpre[i] + bbase[blockIdx.x];
        off[i] = o;
        cursor[i] = o;
    }
    if (i == 0) off[N_NODES] = totE[0];
}

// csr_fill: records src AND dst per CSR slot.
__global__ void csr_fill(const void* ei, const int* __restrict__ flags,
                         int* __restrict__ cursor, int* __restrict__ srcs,
                         int* __restrict__ dsts, int E)
{
    int i = blockIdx.x * blockDim.x + threadIdx.x;
    if (i >= E) return;
    int is64 = flags[0];
    int d = clampi(ld_idx(ei, (long)E + i, is64), N_NODES - 1);
    int s = clampi(ld_idx(ei, i, is64), N_NODES - 1);
    int p = atomicAdd(&cursor[d], 1);
    srcs[p] = s;
    dsts[p] = d;
}

// ---------------------------------------------------------------------------
__global__ void conv_pad_bf16(const float* __restrict__ src, ushort_t* __restrict__ dst,
                              int K, int Kp, long M)
{
    long total = M * Kp;
    long stride = (long)gridDim.x * blockDim.x;
    for (long i = (long)blockIdx.x * blockDim.x + threadIdx.x; i < total; i += stride) {
        long n = i / Kp;
        int k = (int)(i - n * Kp);
        dst[i] = (k < K) ? f2bf(src[n * K + k]) : (ushort_t)0;
    }
}

// ---------------------------------------------------------------------------
// fused weight prep: y=0 -> WT rows [0,HC) = bf16 W^T (padded);
// y=1 -> WT rows [HC,HC+8) = bf16 att-projection columns.
// ---------------------------------------------------------------------------
__global__ void prep_weights(const float* __restrict__ W, const float* __restrict__ att,
                             ushort_t* __restrict__ WT, int K, int Kp, int C, int HC)
{
    int i = blockIdx.x * blockDim.x + threadIdx.x;
    if (blockIdx.y == 0) {
        int nch = Kp >> 3;
        if (i >= HC * nch) return;
        int n = i / nch, c8 = i - n * nch;
#pragma unroll
        for (int e = 0; e < 8; ++e) {
            int k = c8 * 8 + e;
            WT[(long)n * Kp + k] = (k < K) ? f2bf(W[(long)k * HC + n]) : (ushort_t)0;
        }
    } else {
        if (i >= Kp * HEADS) return;
        int k = i >> 2, h = i & 3;
        float s1 = 0.f, s2 = 0.f;
        if (k < K) {
            const float* wrow = W + (long)k * HC + h * C;
            const float* ad = att + h * 2 * C;
            const float* as = ad + C;
            for (int c = 0; c < C; ++c) { float w = wrow[c]; s1 += w * ad[c]; s2 += w * as[c]; }
        }
        WT[(long)(HC + h) * Kp + k]     = f2bf(s1);
        WT[(long)(HC + 4 + h) * Kp + k] = f2bf(s2);
    }
}

// ---------------------------------------------------------------------------
// Per-CSR-slot softmax over heads, logits from XHb's extra columns.
// ---------------------------------------------------------------------------
__global__ void edge_alpha_csr(const int* __restrict__ srcs, const int* __restrict__ dsts,
                               const ushort_t* __restrict__ xh, int ldx, int HC,
                               float* __restrict__ alphac, int E)
{
    int p = blockIdx.x * blockDim.x + threadIdx.x;
    if (p >= E) return;
    int s = srcs[p];
    int d = dsts[p];
    ushort4_t li = *(const ushort4_t*)&xh[(long)d * ldx + HC];
    ushort4_t lj = *(const ushort4_t*)&xh[(long)s * ldx + HC + 4];
    float a[HEADS], m = -1e30f;
#pragma unroll
    for (int h = 0; h < HEADS; ++h) {
        float v = bf2f(li[h]) + bf2f(lj[h]);
        v = (v > 0.f) ? v : 0.2f * v;
        a[h] = v;
        m = fmaxf(m, v);
    }
    float sum = 0.f;
#pragma unroll
    for (int h = 0; h < HEADS; ++h) { a[h] = __expf(a[h] - m); sum += a[h]; }
    float inv = 1.f / sum;
    f32x4 o;
#pragma unroll
    for (int h = 0; h < HEADS; ++h) o[h] = a[h] * inv;
    *(f32x4*)&alphac[(long)p * HEADS] = o;
}

// ---------------------------------------------------------------------------
// bf16 MFMA GEMM: BM=256 BN=128 BK=64, 8 waves (4x2), wave tile 64x64,
// XOR-swizzled LDS, reg-staged global loads, T1 XCD swizzle.
// ---------------------------------------------------------------------------
#define BM 256
#define BN 128
#define BK 64
#define NXCD 8
__global__ __launch_bounds__(512) void gemm_bf16(const ushort_t* __restrict__ A,
                                                 const ushort_t* __restrict__ WT,
                                                 ushort_t* __restrict__ C,
                                                 int M, int FC, int Kp, int ncols)
{
    const int nwg = gridDim.x;
    const int bid = blockIdx.x;
    const int q = nwg >> 3, r = nwg & (NXCD - 1);
    const int k = bid & (NXCD - 1), i = bid >> 3;
    const int wu = (k < r) ? k * (q + 1) + i
                           : r * (q + 1) + (k - r) * q + i;
    const int rowb = wu / ncols;
    const int colb_i = wu - rowb * ncols;
    const int row0 = rowb * BM;
    const int colb = colb_i * BN;

    __shared__ ushort_t As[BM * BK];   // 32 KB
    __shared__ ushort_t Bs[BN * BK];   // 16 KB
    const int tid = threadIdx.x;
    const int lane = tid & 63;
    const int wid = tid >> 6;          // 0..7
    const int wm = wid >> 1, wn = wid & 1;   // 4 x 2 wave grid

    f32x4 acc[4][4];
#pragma unroll
    for (int a = 0; a < 4; ++a)
#pragma unroll
        for (int b = 0; b < 4; ++b) { f32x4 z = {0.f, 0.f, 0.f, 0.f}; acc[a][b] = z; }

    short8 ra[4], rb[2];

    auto loadG = [&](int k0) {
#pragma unroll
        for (int u = 0; u < 4; ++u) {
            int id = u * 512 + tid;            // 0..2047 -> 256 rows x 8 j
            int row = id >> 3, j = id & 7;
            long grow = min(row0 + row, M - 1);
            ra[u] = *(const short8*)&A[grow * Kp + k0 + j * 8];
        }
#pragma unroll
        for (int u = 0; u < 2; ++u) {
            int id = u * 512 + tid;            // 0..1023 -> 128 rows x 8 j
            int row = id >> 3, j = id & 7;
            long gcol = min(colb + row, FC - 1);
            rb[u] = *(const short8*)&WT[gcol * Kp + k0 + j * 8];
        }
    };

    loadG(0);
    for (int k0 = 0; k0 < Kp; k0 += BK) {
        __syncthreads();
#pragma unroll
        for (int u = 0; u < 4; ++u) {
            int id = u * 512 + tid;
            int row = id >> 3, j = id & 7;
            *(short8*)&As[row * BK + ((j ^ (row & 7)) << 3)] = ra[u];
        }
#pragma unroll
        for (int u = 0; u < 2; ++u) {
            int id = u * 512 + tid;
            int row = id >> 3, j = id & 7;
            *(short8*)&Bs[row * BK + ((j ^ (row & 7)) << 3)] = rb[u];
        }
        __syncthreads();
        if (k0 + BK < Kp) loadG(k0 + BK);
#pragma unroll
        for (int ks = 0; ks < 2; ++ks) {
            short8 af[4], bfr[4];
            const int jr = ks * 4 + (lane >> 4);
#pragma unroll
            for (int fm = 0; fm < 4; ++fm) {
                int row = wm * 64 + fm * 16 + (lane & 15);
                af[fm] = *(const short8*)&As[row * BK + ((jr ^ (row & 7)) << 3)];
            }
#pragma unroll
            for (int fn = 0; fn < 4; ++fn) {
                int row = wn * 64 + fn * 16 + (lane & 15);
                bfr[fn] = *(const short8*)&Bs[row * BK + ((jr ^ (row & 7)) << 3)];
            }
#pragma unroll
            for (int fm = 0; fm < 4; ++fm)
#pragma unroll
                for (int fn = 0; fn < 4; ++fn)
                    acc[fm][fn] = __builtin_amdgcn_mfma_f32_16x16x32_bf16(
                        af[fm], bfr[fn], acc[fm][fn], 0, 0, 0);
        }
    }

#pragma unroll
    for (int fm = 0; fm < 4; ++fm) {
        int rbase = row0 + wm * 64 + fm * 16 + (lane >> 4) * 4;
#pragma unroll
        for (int fn = 0; fn < 4; ++fn) {
            int col = colb + wn * 64 + fn * 16 + (lane & 15);
            if (col >= FC) continue;
#pragma unroll
            for (int u = 0; u < 4; ++u) {
                int gr = rbase + u;
                if (gr < M) C[(long)gr * FC + col] = f2bf(acc[fm][fn][u]);
            }
        }
    }
}

// ---------------------------------------------------------------------------
// CSR gather, layers 1/2: grid (node-blocks, col-chunk), edge loop x2 MLP.
// ---------------------------------------------------------------------------
__global__ __launch_bounds__(256) void gat_gather_all(const int* __restrict__ off,
                                                      const int* __restrict__ srcs,
                                                      const float* __restrict__ alphac,
                                                      const ushort_t* __restrict__ xh, int ldx,
                                                      const float* __restrict__ bias,
                                                      ushort_t* __restrict__ outb, int ldo,
                                                      int HC, int FC)
{
    const int wv = threadIdx.x >> 6, lane = threadIdx.x & 63;
    const int n = blockIdx.x * 4 + wv;
    if (n >= N_NODES) return;
    const int base = (blockIdx.y << 8) + lane * 4;
    if (base >= HC) return;

    f32x4 acc0 = {0.f, 0.f, 0.f, 0.f};
    f32x4 acc1 = {0.f, 0.f, 0.f, 0.f};

    const int s0 = off[n], s1 = off[n + 1];
    int i = s0;
    for (; i + 1 < s1; i += 2) {
        f32x4 alA = *(const f32x4*)&alphac[(long)i * HEADS];
        f32x4 alB = *(const f32x4*)&alphac[(long)(i + 1) * HEADS];
        int sA = srcs[i], sB = srcs[i + 1];
        ushort4_t vA = *(const ushort4_t*)&xh[(long)sA * ldx + base];
        ushort4_t vB = *(const ushort4_t*)&xh[(long)sB * ldx + base];
#pragma unroll
        for (int j = 0; j < 4; ++j) {
            int c = base + j;
            float wA = (c < FC) ? alA[0] : (c < 2 * FC) ? alA[1]
                      : (c < 3 * FC) ? alA[2] : alA[3];
            float wB = (c < FC) ? alB[0] : (c < 2 * FC) ? alB[1]
                      : (c < 3 * FC) ? alB[2] : alB[3];
            acc0[j] += wA * bf2f(vA[j]);
            acc1[j] += wB * bf2f(vB[j]);
        }
    }
    if (i < s1) {
        f32x4 al = *(const f32x4*)&alphac[(long)i * HEADS];
        int s = srcs[i];
        ushort4_t v = *(const ushort4_t*)&xh[(long)s * ldx + base];
#pragma unroll
        for (int j = 0; j < 4; ++j) {
            int c = base + j;
            float w = (c < FC) ? al[0] : (c < 2 * FC) ? al[1]
                     : (c < 3 * FC) ? al[2] : al[3];
            acc0[j] += w * bf2f(v[j]);
        }
    }

    ushort4_t o;
#pragma unroll
    for (int j = 0; j < 4; ++j)
        o[j] = f2bf(fmaxf(acc0[j] + acc1[j] + bias[base + j], 0.f));
    *(ushort4_t*)&outb[(long)n * ldo + base] = o;
}

// ---------------------------------------------------------------------------
// Layer 3 fused pool: flat edge stream, 1-deep prefetch, NSPLIT=32,
// plain coalesced f32x4 partial-max stores.
// ---------------------------------------------------------------------------
#define NSPLIT 32
__global__ __launch_bounds__(256) void pool_gather(const int* __restrict__ off,
                                                   const int* __restrict__ srcs,
                                                   const float* __restrict__ alphac,
                                                   const ushort_t* __restrict__ xh, int ldx,
                                                   const float* __restrict__ bias,
                                                   const int* __restrict__ gstart,
                                                   float* __restrict__ PMAX,
                                                   int HC, int FC)
{
    const int g = blockIdx.x / NSPLIT;
    const int sp = blockIdx.x - g * NSPLIT;
    const int col = blockIdx.y * 1024 + threadIdx.x * 4;
    if (col >= HC) return;
    const int h = col / FC;
    const ushort_t* xcol = xh + col;

    const int n0 = gstart[g], n1 = gstart[g + 1];
    const int len = n1 - n0;
    const int chn = (len + NSPLIT - 1) / NSPLIT;
    const int na = n0 + sp * chn;
    const int nb = min(na + chn, n1);

    f32x4 gmax = {0.f, 0.f, 0.f, 0.f};
    if (na < nb) {
        f32x4 bc = *(const f32x4*)&bias[col];
        float accv[4] = {0.f, 0.f, 0.f, 0.f};

        int i = off[na];
        const int iend = off[nb];
        int cur = na;
        int cur_end = off[na + 1];

        while (i == cur_end && cur < nb) {
#pragma unroll
            for (int j = 0; j < 4; ++j) {
                gmax[j] = fmaxf(gmax[j], fmaxf(accv[j] + bc[j], 0.f));
                accv[j] = 0.f;
            }
            ++cur;
            if (cur < nb) cur_end = off[cur + 1];
        }

        float wq = 0.f;
        ushort4_t vq = {0, 0, 0, 0};
        if (i < iend) {
            wq = alphac[(long)i * HEADS + h];
            vq = *(const ushort4_t*)&xcol[(long)srcs[i] * ldx];
        }
        while (i < iend) {
            float w0 = wq;
            ushort4_t v0 = vq;
            if (i + 1 < iend) {
                wq = alphac[(long)(i + 1) * HEADS + h];
                vq = *(const ushort4_t*)&xcol[(long)srcs[i + 1] * ldx];
            }
#pragma unroll
            for (int j = 0; j < 4; ++j) accv[j] += w0 * bf2f(v0[j]);
            ++i;
            while (i == cur_end && cur < nb) {
#pragma unroll
                for (int j = 0; j < 4; ++j) {
                    gmax[j] = fmaxf(gmax[j], fmaxf(accv[j] + bc[j], 0.f));
                    accv[j] = 0.f;
                }
                ++cur;
                if (cur < nb) cur_end = off[cur + 1];
            }
        }
    }
    *(f32x4*)&PMAX[(long)(g * NSPLIT + sp) * 1248 + col] = gmax;
}

__global__ void pmax_red(const float* __restrict__ PMAX, float* __restrict__ G)
{
    int i = blockIdx.x * 256 + threadIdx.x;
    if (i >= N_GRAPHS * 1248) return;
    int g = i / 1248;
    int col = i - g * 1248;
    float m = 0.f;
#pragma unroll
    for (int sp = 0; sp < NSPLIT; ++sp)
        m = fmaxf(m, PMAX[(long)(g * NSPLIT + sp) * 1248 + col]);
    G[i] = m;
}

// ---------------------------------------------------------------------------
// MLP head, split-K (deterministic fixed-order reduce).
// ---------------------------------------------------------------------------
__global__ __launch_bounds__(256) void head_g1_sk(const float* __restrict__ Gp,
                                                  const float* __restrict__ W,
                                                  float* __restrict__ HP)
{
    __shared__ float a0[156], a1[156];
    const int m0 = blockIdx.x * 2;
    const int ks = blockIdx.y;
    const int k0 = ks * 156;
    if (threadIdx.x < 156) {
        a0[threadIdx.x] = Gp[(long)m0 * 1248 + k0 + threadIdx.x];
        a1[threadIdx.x] = Gp[(long)(m0 + 1) * 1248 + k0 + threadIdx.x];
    }
    __syncthreads();
    const int n4 = threadIdx.x * 4;
    float c0[4] = {}, c1[4] = {};
    for (int k = 0; k < 156; ++k) {
        f32x4 b = *(const f32x4*)&W[(long)(k0 + k) * 1024 + n4];
        float av0 = a0[k], av1 = a1[k];
#pragma unroll
        for (int j = 0; j < 4; ++j) { c0[j] += av0 * b[j]; c1[j] += av1 * b[j]; }
    }
    float* hp = HP + ((long)ks * 256 + m0) * 1024;
#pragma unroll
    for (int j = 0; j < 4; ++j) {
        hp[n4 + j]        = c0[j];
        hp[1024 + n4 + j] = c1[j];
    }
}

__global__ void head_g1_red(const float* __restrict__ HP,
                            const float* __restrict__ bias,
                            float* __restrict__ out)
{
    int i = blockIdx.x * 256 + threadIdx.x;
    float s = 0.f;
#pragma unroll
    for (int ks = 0; ks < 8; ++ks) s += HP[(long)ks * 262144 + i];
    out[i] = fmaxf(s + bias[i & 1023], 0.f);
}

__global__ __launch_bounds__(256) void head_g2_sk(const float* __restrict__ G1,
                                                  const float* __restrict__ W,
                                                  float* __restrict__ HP)
{
    __shared__ float a[2][128];
    const int m0 = blockIdx.x * 2;
    const int ks = blockIdx.y;
    const int k0 = ks * 128;
    if (threadIdx.x < 128)
        a[0][threadIdx.x] = G1[(long)m0 * 1024 + k0 + threadIdx.x];
    else
        a[1][threadIdx.x - 128] = G1[(long)(m0 + 1) * 1024 + k0 + threadIdx.x - 128];
    __syncthreads();
    const int nn = threadIdx.x & 127;
    const int r = threadIdx.x >> 7;
    float acc = 0.f;
    for (int k = 0; k < 128; ++k)
        acc += a[r][k] * W[(long)(k0 + k) * 128 + nn];
    HP[((long)ks * 256 + m0 + r) * 128 + nn] = acc;
}

__global__ void head_g2_red(const float* __restrict__ HP,
                            const float* __restrict__ bias,
                            float* __restrict__ out)
{
    int i = blockIdx.x * 256 + threadIdx.x;
    float s = 0.f;
#pragma unroll
    for (int ks = 0; ks < 8; ++ks) s += HP[(long)ks * 32768 + i];
    out[i] = s + bias[i & 127];
}

__global__ __launch_bounds__(256) void head_g3(const float* __restrict__ G2,
                                               const float* __restrict__ Wo,
                                               const float* __restrict__ bo,
                                               float* __restrict__ out)
{
    const int wv = threadIdx.x >> 6, lane = threadIdx.x & 63;
    const int m = blockIdx.x * 4 + wv;
    if (m >= N_GRAPHS) return;
    float s = G2[(long)m * 128 + lane] * Wo[lane]
            + G2[(long)m * 128 + 64 + lane] * Wo[64 + lane];
#pragma unroll
    for (int o = 32; o; o >>= 1) s += __shfl_down(s, o);
    if (lane == 0) out[m] = s + bo[0];
}

// ---------------------------------------------------------------------------
extern "C" void kernel_launch(void* const* d_in, const int* in_sizes, int n_in,
                              void* d_out, int out_size, void* d_ws, size_t ws_size,
                              hipStream_t stream)
{
    const float* x    = (const float*)d_in[0];
    const void*  ei   = d_in[1];
    const void*  batch= d_in[2];
    const float* W1   = (const float*)d_in[3];
    const float* att1 = (const float*)d_in[4];
    const float* b1   = (const float*)d_in[5];
    const float* W2   = (const float*)d_in[6];
    const float* att2 = (const float*)d_in[7];
    const float* b2   = (const float*)d_in[8];
    const float* W3   = (const float*)d_in[9];
    const float* att3 = (const float*)d_in[10];
    const float* b3   = (const float*)d_in[11];
    const float* Wg1  = (const float*)d_in[12];
    const float* bg1  = (const float*)d_in[13];
    const float* Wg2  = (const float*)d_in[14];
    const float* bg2  = (const float*)d_in[15];
    const float* Wo   = (const float*)d_in[16];
    const float* bo   = (const float*)d_in[17];

    const int N = N_NODES;
    const int E = in_sizes[1] / 2;

    // ---- workspace layout (float units), ~148.5 MB ----
    float* ws = (float*)d_ws;
    ushort_t* H1b  = (ushort_t*)ws;
    ushort_t* H2b  = (ushort_t*)(ws + 4800000);
    ushort_t* ABF1 = (ushort_t*)(ws + 14400000);
    ushort_t* XHb  = (ushort_t*)(ws + 16320000);
    ushort_t* WT   = (ushort_t*)(ws + 35160000);
    float* ALPHAC= ws + 35680000;
    float* G     = ws + 36088192;
    float* G1    = ws + 36407680;
    float* G2    = ws + 36669824;
    int*   INDEG = (int*)(ws + 36702592);
    int*   OFF   = (int*)(ws + 36732592);
    int*   CURS  = (int*)(ws + 36762593);
    int*   SRCS  = (int*)(ws + 36892593);
    int*   FLAGS = (int*)(ws + 36992593);
    int*   GCNT  = (int*)(ws + 36992595);
    int*   GSTART= (int*)(ws + 36992851);
    int*   LOCPRE= (int*)(ws + 36993108);
    int*   BSUM  = (int*)(ws + 37023108);
    int*   BBASE = (int*)(ws + 37023226);
    int*   TOTE  = (int*)(ws + 37023344);
    int*   DSTS  = (int*)(ws + 37023345);
    float* PMAX  = ws;
    float* HP1   = ws;
    float* HP2   = ws + 2100000;

    dim3 blk(256);

    detect_fmt<<<dim3(1), blk, 0, stream>>>(ei, batch, E, FLAGS);
    init_zero<<<dim3((N + 255) / 256), blk, 0, stream>>>(INDEG, GCNT);
    zero_pads<<<dim3((N + 255) / 256), blk, 0, stream>>>(H1b, H2b);

    csr_hist<<<dim3((E + 255) / 256), blk, 0, stream>>>(ei, batch, FLAGS, INDEG, GCNT, E);
    scan_a<<<dim3(NBLK_SCAN), blk, 0, stream>>>(INDEG, LOCPRE, BSUM);
    scan_b<<<dim3(1), blk, 0, stream>>>(BSUM, BBASE, TOTE, GCNT, GSTART);
    scan_c<<<dim3(NBLK_SCAN), blk, 0, stream>>>(LOCPRE, BBASE, TOTE, OFF, CURS);
    csr_fill<<<dim3((E + 255) / 256), blk, 0, stream>>>(ei, FLAGS, CURS, SRCS, DSTS, E);

    conv_pad_bf16<<<dim3(8192), blk, 0, stream>>>(x, ABF1, 78, 128, (long)N);

    struct Layer {
        const ushort_t* Abf; int Kp; int K;
        const float *W, *att, *b;
        int C, HC;
        ushort_t* outb; int ldo;
        int pool;
    };
    Layer L[3] = {
        { ABF1, 128,  78, W1, att1, b1,  78,  312, H1b, 320, 0 },
        { H1b,  320, 312, W2, att2, b2, 156,  624, H2b, 640, 0 },
        { H2b,  640, 624, W3, att3, b3, 312, 1248, nullptr, 0, 1 },
    };

    for (int li = 0; li < 3; ++li) {
        const Layer& l = L[li];
        const int FCX = l.HC + 8;              // features + 8 logit cols
        int nch = l.Kp >> 3;
        int gx = (max(l.HC * nch, l.Kp * HEADS) + 255) / 256;
        prep_weights<<<dim3(gx, 2), blk, 0, stream>>>(l.W, l.att, WT, l.K, l.Kp, l.C, l.HC);

        // one GEMM: XHb[N][FCX] = A @ WT^T  (features + logits), BM=256 tile
        int ncols = (FCX + BN - 1) / BN;
        int nrows = (N + BM - 1) / BM;
        gemm_bf16<<<dim3(ncols * nrows), dim3(512), 0, stream>>>(l.Abf, WT, XHb, N, FCX, l.Kp, ncols);

        // per-edge alpha from XHb logit columns
        edge_alpha_csr<<<dim3((E + 255) / 256), blk, 0, stream>>>(
            SRCS, DSTS, XHb, FCX, l.HC, ALPHAC, E);

        if (l.pool) {
            dim3 pg(N_GRAPHS * NSPLIT, (l.HC + 1023) / 1024);
            pool_gather<<<pg, blk, 0, stream>>>(OFF, SRCS, ALPHAC, XHb, FCX, l.b,
                                                GSTART, PMAX, l.HC, l.C);
            pmax_red<<<dim3((N_GRAPHS * 1248 + 255) / 256), blk, 0, stream>>>(PMAX, G);
        } else {
            dim3 gg((N + 3) / 4, (l.HC + 255) >> 8);
            gat_gather_all<<<gg, blk, 0, stream>>>(
                OFF, SRCS, ALPHAC, XHb, FCX, l.b, l.outb, l.ldo, l.HC, l.C);
        }
    }

    // ---- MLP head (f32 exact, split-K with fixed-order reduce) ----
    head_g1_sk <<<dim3(N_GRAPHS / 2, 8), blk, 0, stream>>>(G, Wg1, HP1);
    head_g1_red<<<dim3(1024), blk, 0, stream>>>(HP1, bg1, G1);
    head_g2_sk <<<dim3(N_GRAPHS / 2, 8), blk, 0, stream>>>(G1, Wg2, HP2);
    head_g2_red<<<dim3(128), blk, 0, stream>>>(HP2, bg2, G2);
    head_g3    <<<dim3(N_GRAPHS / 4), blk, 0, stream>>>(G2, Wo, bo, (float*)d_out);
}

// Round 20
// 454.694 us; speedup vs baseline: 1.0522x; 1.0522x over previous
//
#include <hip/hip_runtime.h>
#include <hip/hip_bf16.h>

#define N_NODES 30000
#define N_GRAPHS 256
#define HEADS 4
#define NBLK_SCAN ((N_NODES + 255) / 256)   // 118

typedef __attribute__((ext_vector_type(8))) short short8;
typedef __attribute__((ext_vector_type(4))) float f32x4;
typedef __attribute__((ext_vector_type(4))) unsigned short ushort4_t;
typedef unsigned short ushort_t;

__device__ __forceinline__ ushort_t f2bf(float v) {
    __hip_bfloat16 h = __float2bfloat16(v);
    return *reinterpret_cast<ushort_t*>(&h);
}
__device__ __forceinline__ float bf2f(ushort_t u) {
    __hip_bfloat16 h;
    *reinterpret_cast<ushort_t*>(&h) = u;
    return __bfloat162float(h);
}
__device__ __forceinline__ int ld_idx(const void* p, long i, int is64) {
    return is64 ? (int)((const long long*)p)[i] : ((const int*)p)[i];
}
__device__ __forceinline__ int clampi(int v, int hi) {
    return v < 0 ? 0 : (v > hi ? hi : v);
}

// ---------------------------------------------------------------------------
__global__ void detect_fmt(const void* ei, const void* batch, int E, int* flags)
{
    __shared__ int okE, okB;
    if (threadIdx.x == 0) { okE = 1; okB = 1; }
    __syncthreads();
    const long long* e64 = (const long long*)ei;
    const long long* b64 = (const long long*)batch;
    const int nbslot = N_NODES / 2;
    for (int i = threadIdx.x; i < 2048; i += 256) {
        long ei_idx = (long)i * E / 2048;
        long long v = e64[ei_idx];
        if (v < 0 || v >= N_NODES) okE = 0;
        long b_idx = (long)i * nbslot / 2048;
        long long b = b64[b_idx];
        if (b < 0 || b >= N_GRAPHS) okB = 0;
    }
    __syncthreads();
    if (threadIdx.x == 0) { flags[0] = okE; flags[1] = okB; }
}

// ---------------------------------------------------------------------------
__global__ void init_zero(int* __restrict__ indeg, int* __restrict__ gcnt)
{
    int i = blockIdx.x * 256 + threadIdx.x;
    if (i < N_NODES) indeg[i] = 0;
    if (i < N_GRAPHS) gcnt[i] = 0;
}

__global__ void zero_pads(ushort_t* __restrict__ H1b, ushort_t* __restrict__ H2b)
{
    int n = blockIdx.x * blockDim.x + threadIdx.x;
    if (n >= N_NODES) return;
    ushort4_t z = {0, 0, 0, 0};
    *(ushort4_t*)&H1b[(long)n * 320 + 312] = z;
    *(ushort4_t*)&H1b[(long)n * 320 + 316] = z;
#pragma unroll
    for (int q = 0; q < 4; ++q)
        *(ushort4_t*)&H2b[(long)n * 640 + 624 + q * 4] = z;
}

// ---------------------------------------------------------------------------
__global__ void csr_hist(const void* ei, const void* batch, const int* __restrict__ flags,
                         int* __restrict__ indeg, int* __restrict__ gcnt, int E)
{
    int i = blockIdx.x * blockDim.x + threadIdx.x;
    if (i < E) {
        int d = clampi(ld_idx(ei, (long)E + i, flags[0]), N_NODES - 1);
        atomicAdd(&indeg[d], 1);
    }
    if (i < N_NODES) {
        int g = clampi(ld_idx(batch, i, flags[1]), N_GRAPHS - 1);
        atomicAdd(&gcnt[g], 1);
    }
}

// ---------------------------------------------------------------------------
// 3-phase coalesced device scan
// ---------------------------------------------------------------------------
__global__ __launch_bounds__(256) void scan_a(const int* __restrict__ indeg,
                                              int* __restrict__ locpre,
                                              int* __restrict__ bsum)
{
    __shared__ int ps[256];
    const int t = threadIdx.x;
    const int i = blockIdx.x * 256 + t;
    int v = (i < N_NODES) ? indeg[i] : 0;
    ps[t] = v;
    __syncthreads();
    for (int d = 1; d < 256; d <<= 1) {
        int u = (t >= d) ? ps[t - d] : 0;
        __syncthreads();
        ps[t] += u;
        __syncthreads();
    }
    if (i < N_NODES) locpre[i] = ps[t] - v;
    if (t == 255) bsum[blockIdx.x] = ps[255];
}

__global__ __launch_bounds__(256) void scan_b(const int* __restrict__ bsum,
                                              int* __restrict__ bbase,
                                              int* __restrict__ totE,
                                              const int* __restrict__ gcnt,
                                              int* __restrict__ gstart)
{
    __shared__ int ps[256];
    const int t = threadIdx.x;
    int v = (t < NBLK_SCAN) ? bsum[t] : 0;
    ps[t] = v;
    __syncthreads();
    for (int d = 1; d < 256; d <<= 1) {
        int u = (t >= d) ? ps[t - d] : 0;
        __syncthreads();
        ps[t] += u;
        __syncthreads();
    }
    if (t < NBLK_SCAN) bbase[t] = ps[t] - v;
    if (t == 255) totE[0] = ps[255];
    __syncthreads();
    int gv = gcnt[t];
    ps[t] = gv;
    __syncthreads();
    for (int d = 1; d < 256; d <<= 1) {
        int u = (t >= d) ? ps[t - d] : 0;
        __syncthreads();
        ps[t] += u;
        __syncthreads();
    }
    gstart[t + 1] = ps[t];
    if (t == 0) gstart[0] = 0;
}

__global__ void scan_c(const int* __restrict__ locpre, const int* __restrict__ bbase,
                       const int* __restrict__ totE,
                       int* __restrict__ off, int* __restrict__ cursor)
{
    int i = blockIdx.x * 256 + threadIdx.x;
    if (i < N_NODES) {
        int o = locpre[i] + bbase[blockIdx.x];
        off[i] = o;
        cursor[i] = o;
    }
    if (i == 0) off[N_NODES] = totE[0];
}

// csr_fill: records src AND dst per CSR slot.
__global__ void csr_fill(const void* ei, const int* __restrict__ flags,
                         int* __restrict__ cursor, int* __restrict__ srcs,
                         int* __restrict__ dsts, int E)
{
    int i = blockIdx.x * blockDim.x + threadIdx.x;
    if (i >= E) return;
    int is64 = flags[0];
    int d = clampi(ld_idx(ei, (long)E + i, is64), N_NODES - 1);
    int s = clampi(ld_idx(ei, i, is64), N_NODES - 1);
    int p = atomicAdd(&cursor[d], 1);
    srcs[p] = s;
    dsts[p] = d;
}

// ---------------------------------------------------------------------------
__global__ void conv_pad_bf16(const float* __restrict__ src, ushort_t* __restrict__ dst,
                              int K, int Kp, long M)
{
    long total = M * Kp;
    long stride = (long)gridDim.x * blockDim.x;
    for (long i = (long)blockIdx.x * blockDim.x + threadIdx.x; i < total; i += stride) {
        long n = i / Kp;
        int k = (int)(i - n * Kp);
        dst[i] = (k < K) ? f2bf(src[n * K + k]) : (ushort_t)0;
    }
}

// ---------------------------------------------------------------------------
// fused weight prep: y=0 -> WT rows [0,HC) = bf16 W^T (padded);
// y=1 -> WT rows [HC,HC+8) = bf16 att-projection columns.
// ---------------------------------------------------------------------------
__global__ void prep_weights(const float* __restrict__ W, const float* __restrict__ att,
                             ushort_t* __restrict__ WT, int K, int Kp, int C, int HC)
{
    int i = blockIdx.x * blockDim.x + threadIdx.x;
    if (blockIdx.y == 0) {
        int nch = Kp >> 3;
        if (i >= HC * nch) return;
        int n = i / nch, c8 = i - n * nch;
#pragma unroll
        for (int e = 0; e < 8; ++e) {
            int k = c8 * 8 + e;
            WT[(long)n * Kp + k] = (k < K) ? f2bf(W[(long)k * HC + n]) : (ushort_t)0;
        }
    } else {
        if (i >= Kp * HEADS) return;
        int k = i >> 2, h = i & 3;
        float s1 = 0.f, s2 = 0.f;
        if (k < K) {
            const float* wrow = W + (long)k * HC + h * C;
            const float* ad = att + h * 2 * C;
            const float* as = ad + C;
            for (int c = 0; c < C; ++c) { float w = wrow[c]; s1 += w * ad[c]; s2 += w * as[c]; }
        }
        WT[(long)(HC + h) * Kp + k]     = f2bf(s1);
        WT[(long)(HC + 4 + h) * Kp + k] = f2bf(s2);
    }
}

// ---------------------------------------------------------------------------
// Per-CSR-slot softmax over heads, logits from XHb's extra columns.
// ---------------------------------------------------------------------------
__global__ void edge_alpha_csr(const int* __restrict__ srcs, const int* __restrict__ dsts,
                               const ushort_t* __restrict__ xh, int ldx, int HC,
                               float* __restrict__ alphac, int E)
{
    int p = blockIdx.x * blockDim.x + threadIdx.x;
    if (p >= E) return;
    int s = srcs[p];
    int d = dsts[p];
    ushort4_t li = *(const ushort4_t*)&xh[(long)d * ldx + HC];
    ushort4_t lj = *(const ushort4_t*)&xh[(long)s * ldx + HC + 4];
    float a[HEADS], m = -1e30f;
#pragma unroll
    for (int h = 0; h < HEADS; ++h) {
        float v = bf2f(li[h]) + bf2f(lj[h]);
        v = (v > 0.f) ? v : 0.2f * v;
        a[h] = v;
        m = fmaxf(m, v);
    }
    float sum = 0.f;
#pragma unroll
    for (int h = 0; h < HEADS; ++h) { a[h] = __expf(a[h] - m); sum += a[h]; }
    float inv = 1.f / sum;
    f32x4 o;
#pragma unroll
    for (int h = 0; h < HEADS; ++h) o[h] = a[h] * inv;
    *(f32x4*)&alphac[(long)p * HEADS] = o;
}

// ---------------------------------------------------------------------------
// bf16 MFMA GEMM: BM=128 BN=128 BK=64, 4 waves, XOR-swizzled LDS,
// reg-staged global loads, T1 XCD swizzle.  FC includes the 8 logit cols.
// (Proven round-17/18 configuration.)
// ---------------------------------------------------------------------------
#define BM 128
#define BN 128
#define BK 64
#define NXCD 8
__global__ __launch_bounds__(256) void gemm_bf16(const ushort_t* __restrict__ A,
                                                 const ushort_t* __restrict__ WT,
                                                 ushort_t* __restrict__ C,
                                                 int M, int FC, int Kp, int ncols)
{
    const int nwg = gridDim.x;
    const int bid = blockIdx.x;
    const int q = nwg >> 3, r = nwg & (NXCD - 1);
    const int k = bid & (NXCD - 1), i = bid >> 3;
    const int wu = (k < r) ? k * (q + 1) + i
                           : r * (q + 1) + (k - r) * q + i;
    const int rowb = wu / ncols;
    const int colb_i = wu - rowb * ncols;
    const int row0 = rowb * BM;
    const int colb = colb_i * BN;

    __shared__ ushort_t As[BM * BK];
    __shared__ ushort_t Bs[BN * BK];
    const int tid = threadIdx.x;
    const int lane = tid & 63;
    const int wid = tid >> 6;
    const int wm = wid >> 1, wn = wid & 1;

    f32x4 acc[4][4];
#pragma unroll
    for (int a = 0; a < 4; ++a)
#pragma unroll
        for (int b = 0; b < 4; ++b) { f32x4 z = {0.f, 0.f, 0.f, 0.f}; acc[a][b] = z; }

    short8 ra[4], rb[4];

    auto loadG = [&](int k0) {
#pragma unroll
        for (int u = 0; u < 4; ++u) {
            int id = u * 256 + tid;
            int row = id >> 3, j = id & 7;
            long grow = min(row0 + row, M - 1);
            ra[u] = *(const short8*)&A[grow * Kp + k0 + j * 8];
        }
#pragma unroll
        for (int u = 0; u < 4; ++u) {
            int id = u * 256 + tid;
            int row = id >> 3, j = id & 7;
            long gcol = min(colb + row, FC - 1);
            rb[u] = *(const short8*)&WT[gcol * Kp + k0 + j * 8];
        }
    };

    loadG(0);
    for (int k0 = 0; k0 < Kp; k0 += BK) {
        __syncthreads();
#pragma unroll
        for (int u = 0; u < 4; ++u) {
            int id = u * 256 + tid;
            int row = id >> 3, j = id & 7;
            *(short8*)&As[row * BK + ((j ^ (row & 7)) << 3)] = ra[u];
        }
#pragma unroll
        for (int u = 0; u < 4; ++u) {
            int id = u * 256 + tid;
            int row = id >> 3, j = id & 7;
            *(short8*)&Bs[row * BK + ((j ^ (row & 7)) << 3)] = rb[u];
        }
        __syncthreads();
        if (k0 + BK < Kp) loadG(k0 + BK);
#pragma unroll
        for (int ks = 0; ks < 2; ++ks) {
            short8 af[4], bfr[4];
            const int jr = ks * 4 + (lane >> 4);
#pragma unroll
            for (int fm = 0; fm < 4; ++fm) {
                int row = wm * 64 + fm * 16 + (lane & 15);
                af[fm] = *(const short8*)&As[row * BK + ((jr ^ (row & 7)) << 3)];
            }
#pragma unroll
            for (int fn = 0; fn < 4; ++fn) {
                int row = wn * 64 + fn * 16 + (lane & 15);
                bfr[fn] = *(const short8*)&Bs[row * BK + ((jr ^ (row & 7)) << 3)];
            }
#pragma unroll
            for (int fm = 0; fm < 4; ++fm)
#pragma unroll
                for (int fn = 0; fn < 4; ++fn)
                    acc[fm][fn] = __builtin_amdgcn_mfma_f32_16x16x32_bf16(
                        af[fm], bfr[fn], acc[fm][fn], 0, 0, 0);
        }
    }

#pragma unroll
    for (int fm = 0; fm < 4; ++fm) {
        int rbase = row0 + wm * 64 + fm * 16 + (lane >> 4) * 4;
#pragma unroll
        for (int fn = 0; fn < 4; ++fn) {
            int col = colb + wn * 64 + fn * 16 + (lane & 15);
            if (col >= FC) continue;
#pragma unroll
            for (int u = 0; u < 4; ++u) {
                int gr = rbase + u;
                if (gr < M) C[(long)gr * FC + col] = f2bf(acc[fm][fn][u]);
            }
        }
    }
}

// ---------------------------------------------------------------------------
// CSR gather, layers 1/2: grid (node-blocks, col-chunk), edge loop x2 MLP.
// ---------------------------------------------------------------------------
__global__ __launch_bounds__(256) void gat_gather_all(const int* __restrict__ off,
                                                      const int* __restrict__ srcs,
                                                      const float* __restrict__ alphac,
                                                      const ushort_t* __restrict__ xh, int ldx,
                                                      const float* __restrict__ bias,
                                                      ushort_t* __restrict__ outb, int ldo,
                                                      int HC, int FC)
{
    const int wv = threadIdx.x >> 6, lane = threadIdx.x & 63;
    const int n = blockIdx.x * 4 + wv;
    if (n >= N_NODES) return;
    const int base = (blockIdx.y << 8) + lane * 4;
    if (base >= HC) return;

    f32x4 acc0 = {0.f, 0.f, 0.f, 0.f};
    f32x4 acc1 = {0.f, 0.f, 0.f, 0.f};

    const int s0 = off[n], s1 = off[n + 1];
    int i = s0;
    for (; i + 1 < s1; i += 2) {
        f32x4 alA = *(const f32x4*)&alphac[(long)i * HEADS];
        f32x4 alB = *(const f32x4*)&alphac[(long)(i + 1) * HEADS];
        int sA = srcs[i], sB = srcs[i + 1];
        ushort4_t vA = *(const ushort4_t*)&xh[(long)sA * ldx + base];
        ushort4_t vB = *(const ushort4_t*)&xh[(long)sB * ldx + base];
#pragma unroll
        for (int j = 0; j < 4; ++j) {
            int c = base + j;
            float wA = (c < FC) ? alA[0] : (c < 2 * FC) ? alA[1]
                      : (c < 3 * FC) ? alA[2] : alA[3];
            float wB = (c < FC) ? alB[0] : (c < 2 * FC) ? alB[1]
                      : (c < 3 * FC) ? alB[2] : alB[3];
            acc0[j] += wA * bf2f(vA[j]);
            acc1[j] += wB * bf2f(vB[j]);
        }
    }
    if (i < s1) {
        f32x4 al = *(const f32x4*)&alphac[(long)i * HEADS];
        int s = srcs[i];
        ushort4_t v = *(const ushort4_t*)&xh[(long)s * ldx + base];
#pragma unroll
        for (int j = 0; j < 4; ++j) {
            int c = base + j;
            float w = (c < FC) ? al[0] : (c < 2 * FC) ? al[1]
                     : (c < 3 * FC) ? al[2] : al[3];
            acc0[j] += w * bf2f(v[j]);
        }
    }

    ushort4_t o;
#pragma unroll
    for (int j = 0; j < 4; ++j)
        o[j] = f2bf(fmaxf(acc0[j] + acc1[j] + bias[base + j], 0.f));
    *(ushort4_t*)&outb[(long)n * ldo + base] = o;
}

// ---------------------------------------------------------------------------
// Layer 3 fused pool: flat edge stream, 1-deep prefetch, NSPLIT=32,
// plain coalesced f32x4 partial-max stores.
// ---------------------------------------------------------------------------
#define NSPLIT 32
__global__ __launch_bounds__(256) void pool_gather(const int* __restrict__ off,
                                                   const int* __restrict__ srcs,
                                                   const float* __restrict__ alphac,
                                                   const ushort_t* __restrict__ xh, int ldx,
                                                   const float* __restrict__ bias,
                                                   const int* __restrict__ gstart,
                                                   float* __restrict__ PMAX,
                                                   int HC, int FC)
{
    const int g = blockIdx.x / NSPLIT;
    const int sp = blockIdx.x - g * NSPLIT;
    const int col = blockIdx.y * 1024 + threadIdx.x * 4;
    if (col >= HC) return;
    const int h = col / FC;
    const ushort_t* xcol = xh + col;

    const int n0 = gstart[g], n1 = gstart[g + 1];
    const int len = n1 - n0;
    const int chn = (len + NSPLIT - 1) / NSPLIT;
    const int na = n0 + sp * chn;
    const int nb = min(na + chn, n1);

    f32x4 gmax = {0.f, 0.f, 0.f, 0.f};
    if (na < nb) {
        f32x4 bc = *(const f32x4*)&bias[col];
        float accv[4] = {0.f, 0.f, 0.f, 0.f};

        int i = off[na];
        const int iend = off[nb];
        int cur = na;
        int cur_end = off[na + 1];

        while (i == cur_end && cur < nb) {
#pragma unroll
            for (int j = 0; j < 4; ++j) {
                gmax[j] = fmaxf(gmax[j], fmaxf(accv[j] + bc[j], 0.f));
                accv[j] = 0.f;
            }
            ++cur;
            if (cur < nb) cur_end = off[cur + 1];
        }

        float wq = 0.f;
        ushort4_t vq = {0, 0, 0, 0};
        if (i < iend) {
            wq = alphac[(long)i * HEADS + h];
            vq = *(const ushort4_t*)&xcol[(long)srcs[i] * ldx];
        }
        while (i < iend) {
            float w0 = wq;
            ushort4_t v0 = vq;
            if (i + 1 < iend) {
                wq = alphac[(long)(i + 1) * HEADS + h];
                vq = *(const ushort4_t*)&xcol[(long)srcs[i + 1] * ldx];
            }
#pragma unroll
            for (int j = 0; j < 4; ++j) accv[j] += w0 * bf2f(v0[j]);
            ++i;
            while (i == cur_end && cur < nb) {
#pragma unroll
                for (int j = 0; j < 4; ++j) {
                    gmax[j] = fmaxf(gmax[j], fmaxf(accv[j] + bc[j], 0.f));
                    accv[j] = 0.f;
                }
                ++cur;
                if (cur < nb) cur_end = off[cur + 1];
            }
        }
    }
    *(f32x4*)&PMAX[(long)(g * NSPLIT + sp) * 1248 + col] = gmax;
}

__global__ void pmax_red(const float* __restrict__ PMAX, float* __restrict__ G)
{
    int i = blockIdx.x * 256 + threadIdx.x;
    if (i >= N_GRAPHS * 1248) return;
    int g = i / 1248;
    int col = i - g * 1248;
    float m = 0.f;
#pragma unroll
    for (int sp = 0; sp < NSPLIT; ++sp)
        m = fmaxf(m, PMAX[(long)(g * NSPLIT + sp) * 1248 + col]);
    G[i] = m;
}

// ---------------------------------------------------------------------------
// MLP head, split-K (deterministic fixed-order reduce).
// ---------------------------------------------------------------------------
__global__ __launch_bounds__(256) void head_g1_sk(const float* __restrict__ Gp,
                                                  const float* __restrict__ W,
                                                  float* __restrict__ HP)
{
    __shared__ float a0[156], a1[156];
    const int m0 = blockIdx.x * 2;
    const int ks = blockIdx.y;
    const int k0 = ks * 156;
    if (threadIdx.x < 156) {
        a0[threadIdx.x] = Gp[(long)m0 * 1248 + k0 + threadIdx.x];
        a1[threadIdx.x] = Gp[(long)(m0 + 1) * 1248 + k0 + threadIdx.x];
    }
    __syncthreads();
    const int n4 = threadIdx.x * 4;
    float c0[4] = {}, c1[4] = {};
    for (int k = 0; k < 156; ++k) {
        f32x4 b = *(const f32x4*)&W[(long)(k0 + k) * 1024 + n4];
        float av0 = a0[k], av1 = a1[k];
#pragma unroll
        for (int j = 0; j < 4; ++j) { c0[j] += av0 * b[j]; c1[j] += av1 * b[j]; }
    }
    float* hp = HP + ((long)ks * 256 + m0) * 1024;
#pragma unroll
    for (int j = 0; j < 4; ++j) {
        hp[n4 + j]        = c0[j];
        hp[1024 + n4 + j] = c1[j];
    }
}

__global__ void head_g1_red(const float* __restrict__ HP,
                            const float* __restrict__ bias,
                            float* __restrict__ out)
{
    int i = blockIdx.x * 256 + threadIdx.x;
    float s = 0.f;
#pragma unroll
    for (int ks = 0; ks < 8; ++ks) s += HP[(long)ks * 262144 + i];
    out[i] = fmaxf(s + bias[i & 1023], 0.f);
}

__global__ __launch_bounds__(256) void head_g2_sk(const float* __restrict__ G1,
                                                  const float* __restrict__ W,
                                                  float* __restrict__ HP)
{
    __shared__ float a[2][128];
    const int m0 = blockIdx.x * 2;
    const int ks = blockIdx.y;
    const int k0 = ks * 128;
    if (threadIdx.x < 128)
        a[0][threadIdx.x] = G1[(long)m0 * 1024 + k0 + threadIdx.x];
    else
        a[1][threadIdx.x - 128] = G1[(long)(m0 + 1) * 1024 + k0 + threadIdx.x - 128];
    __syncthreads();
    const int nn = threadIdx.x & 127;
    const int r = threadIdx.x >> 7;
    float acc = 0.f;
    for (int k = 0; k < 128; ++k)
        acc += a[r][k] * W[(long)(k0 + k) * 128 + nn];
    HP[((long)ks * 256 + m0 + r) * 128 + nn] = acc;
}

__global__ void head_g2_red(const float* __restrict__ HP,
                            const float* __restrict__ bias,
                            float* __restrict__ out)
{
    int i = blockIdx.x * 256 + threadIdx.x;
    float s = 0.f;
#pragma unroll
    for (int ks = 0; ks < 8; ++ks) s += HP[(long)ks * 32768 + i];
    out[i] = s + bias[i & 127];
}

__global__ __launch_bounds__(256) void head_g3(const float* __restrict__ G2,
                                               const float* __restrict__ Wo,
                                               const float* __restrict__ bo,
                                               float* __restrict__ out)
{
    const int wv = threadIdx.x >> 6, lane = threadIdx.x & 63;
    const int m = blockIdx.x * 4 + wv;
    if (m >= N_GRAPHS) return;
    float s = G2[(long)m * 128 + lane] * Wo[lane]
            + G2[(long)m * 128 + 64 + lane] * Wo[64 + lane];
#pragma unroll
    for (int o = 32; o; o >>= 1) s += __shfl_down(s, o);
    if (lane == 0) out[m] = s + bo[0];
}

// ---------------------------------------------------------------------------
extern "C" void kernel_launch(void* const* d_in, const int* in_sizes, int n_in,
                              void* d_out, int out_size, void* d_ws, size_t ws_size,
                              hipStream_t stream)
{
    const float* x    = (const float*)d_in[0];
    const void*  ei   = d_in[1];
    const void*  batch= d_in[2];
    const float* W1   = (const float*)d_in[3];
    const float* att1 = (const float*)d_in[4];
    const float* b1   = (const float*)d_in[5];
    const float* W2   = (const float*)d_in[6];
    const float* att2 = (const float*)d_in[7];
    const float* b2   = (const float*)d_in[8];
    const float* W3   = (const float*)d_in[9];
    const float* att3 = (const float*)d_in[10];
    const float* b3   = (const float*)d_in[11];
    const float* Wg1  = (const float*)d_in[12];
    const float* bg1  = (const float*)d_in[13];
    const float* Wg2  = (const float*)d_in[14];
    const float* bg2  = (const float*)d_in[15];
    const float* Wo   = (const float*)d_in[16];
    const float* bo   = (const float*)d_in[17];

    const int N = N_NODES;
    const int E = in_sizes[1] / 2;

    // ---- workspace layout (float units), ~148.5 MB ----
    float* ws = (float*)d_ws;
    ushort_t* H1b  = (ushort_t*)ws;
    ushort_t* H2b  = (ushort_t*)(ws + 4800000);
    ushort_t* ABF1 = (ushort_t*)(ws + 14400000);
    ushort_t* XHb  = (ushort_t*)(ws + 16320000);
    ushort_t* WT   = (ushort_t*)(ws + 35160000);
    float* ALPHAC= ws + 35680000;
    float* G     = ws + 36088192;
    float* G1    = ws + 36407680;
    float* G2    = ws + 36669824;
    int*   INDEG = (int*)(ws + 36702592);
    int*   OFF   = (int*)(ws + 36732592);
    int*   CURS  = (int*)(ws + 36762593);
    int*   SRCS  = (int*)(ws + 36892593);
    int*   FLAGS = (int*)(ws + 36992593);
    int*   GCNT  = (int*)(ws + 36992595);
    int*   GSTART= (int*)(ws + 36992851);
    int*   LOCPRE= (int*)(ws + 36993108);
    int*   BSUM  = (int*)(ws + 37023108);
    int*   BBASE = (int*)(ws + 37023226);
    int*   TOTE  = (int*)(ws + 37023344);
    int*   DSTS  = (int*)(ws + 37023345);
    float* PMAX  = ws;
    float* HP1   = ws;
    float* HP2   = ws + 2100000;

    dim3 blk(256);

    detect_fmt<<<dim3(1), blk, 0, stream>>>(ei, batch, E, FLAGS);
    init_zero<<<dim3((N + 255) / 256), blk, 0, stream>>>(INDEG, GCNT);
    zero_pads<<<dim3((N + 255) / 256), blk, 0, stream>>>(H1b, H2b);

    csr_hist<<<dim3((E + 255) / 256), blk, 0, stream>>>(ei, batch, FLAGS, INDEG, GCNT, E);
    scan_a<<<dim3(NBLK_SCAN), blk, 0, stream>>>(INDEG, LOCPRE, BSUM);
    scan_b<<<dim3(1), blk, 0, stream>>>(BSUM, BBASE, TOTE, GCNT, GSTART);
    scan_c<<<dim3(NBLK_SCAN), blk, 0, stream>>>(LOCPRE, BBASE, TOTE, OFF, CURS);
    csr_fill<<<dim3((E + 255) / 256), blk, 0, stream>>>(ei, FLAGS, CURS, SRCS, DSTS, E);

    conv_pad_bf16<<<dim3(8192), blk, 0, stream>>>(x, ABF1, 78, 128, (long)N);

    struct Layer {
        const ushort_t* Abf; int Kp; int K;
        const float *W, *att, *b;
        int C, HC;
        ushort_t* outb; int ldo;
        int pool;
    };
    Layer L[3] = {
        { ABF1, 128,  78, W1, att1, b1,  78,  312, H1b, 320, 0 },
        { H1b,  320, 312, W2, att2, b2, 156,  624, H2b, 640, 0 },
        { H2b,  640, 624, W3, att3, b3, 312, 1248, nullptr, 0, 1 },
    };

    for (int li = 0; li < 3; ++li) {
        const Layer& l = L[li];
        const int FCX = l.HC + 8;              // features + 8 logit cols
        int nch = l.Kp >> 3;
        int gx = (max(l.HC * nch, l.Kp * HEADS) + 255) / 256;
        prep_weights<<<dim3(gx, 2), blk, 0, stream>>>(l.W, l.att, WT, l.K, l.Kp, l.C, l.HC);

        // one GEMM: XHb[N][FCX] = A @ WT^T  (features + logits)
        int ncols = (FCX + BN - 1) / BN;
        int nrows = (N + BM - 1) / BM;
        gemm_bf16<<<dim3(ncols * nrows), blk, 0, stream>>>(l.Abf, WT, XHb, N, FCX, l.Kp, ncols);

        // per-edge alpha from XHb logit columns
        edge_alpha_csr<<<dim3((E + 255) / 256), blk, 0, stream>>>(
            SRCS, DSTS, XHb, FCX, l.HC, ALPHAC, E);

        if (l.pool) {
            dim3 pg(N_GRAPHS * NSPLIT, (l.HC + 1023) / 1024);
            pool_gather<<<pg, blk, 0, stream>>>(OFF, SRCS, ALPHAC, XHb, FCX, l.b,
                                                GSTART, PMAX, l.HC, l.C);
            pmax_red<<<dim3((N_GRAPHS * 1248 + 255) / 256), blk, 0, stream>>>(PMAX, G);
        } else {
            dim3 gg((N + 3) / 4, (l.HC + 255) >> 8);
            gat_gather_all<<<gg, blk, 0, stream>>>(
                OFF, SRCS, ALPHAC, XHb, FCX, l.b, l.outb, l.ldo, l.HC, l.C);
        }
    }

    // ---- MLP head (f32 exact, split-K with fixed-order reduce) ----
    head_g1_sk <<<dim3(N_GRAPHS / 2, 8), blk, 0, stream>>>(G, Wg1, HP1);
    head_g1_red<<<dim3(1024), blk, 0, stream>>>(HP1, bg1, G1);
    head_g2_sk <<<dim3(N_GRAPHS / 2, 8), blk, 0, stream>>>(G1, Wg2, HP2);
    head_g2_red<<<dim3(128), blk, 0, stream>>>(HP2, bg2, G2);
    head_g3    <<<dim3(N_GRAPHS / 4), blk, 0, stream>>>(G2, Wo, bo, (float*)d_out);
}